// Round 11
// baseline (3828.680 us; speedup 1.0000x reference)
//
#include <hip/hip_runtime.h>

typedef float v2f __attribute__((ext_vector_type(2)));
typedef float v4f __attribute__((ext_vector_type(4)));

#define D_IN 14
#define HID  32
#define XT   16   // timesteps per xproj block

#define LOG2E      1.4426950408889634f
#define TWO_LOG2E  2.8853900817779268f

__device__ __forceinline__ float rcpf(float x) { return __builtin_amdgcn_rcpf(x); }

#if __has_builtin(__builtin_amdgcn_exp2f)
__device__ __forceinline__ float exp2ff(float x) { return __builtin_amdgcn_exp2f(x); }
#else
__device__ __forceinline__ float exp2ff(float x) { return exp2f(x); }
#endif

// DPP row_ror:N (0x120+N): independent depth-1 rotations within 16-lane rows.
template<int CTRL>
__device__ __forceinline__ float dppf(float x) {
    return __int_as_float(__builtin_amdgcn_mov_dpp(
        __float_as_int(x), CTRL, 0xf, 0xf, true));
}

// Probed-direction exchanges: 3 ops, EXACT partner value.
// mask (built once in prologue by probing with lane ids) says, per lane,
// whether register a or b holds the partner's value after the swap.
__device__ __forceinline__ float xchg16_sel(float x, unsigned long long mk) {
    float a = x, b, y;
    asm("v_mov_b32 %0, %1" : "=&v"(b) : "v"(x));
    asm("v_permlane16_swap_b32 %0, %1" : "+v"(a), "+v"(b));
    asm("v_cndmask_b32 %0, %1, %2, %3" : "=v"(y) : "v"(b), "v"(a), "s"(mk));
    return y;
}
__device__ __forceinline__ float xchg32_sel(float x, unsigned long long mk) {
    float a = x, b, y;
    asm("v_mov_b32 %0, %1" : "=&v"(b) : "v"(x));
    asm("v_permlane32_swap_b32 %0, %1" : "+v"(a), "+v"(b));
    asm("v_cndmask_b32 %0, %1, %2, %3" : "=v"(y) : "v"(b), "v"(a), "s"(mk));
    return y;
}

// ---------------- phase 1: x projection (parallel, bit-exact) ----------
// Identical to round 10 (passed): stores the UNROUNDED v2f accumulator pair.
// Layout: xp[t][m][lane 0..63][4] floats = {accA.x, accA.y, accB.x, accB.y}.
__global__ __launch_bounds__(128)
void xproj_kernel(const float* __restrict__ x,
                  const float* __restrict__ W_ih,
                  const float* __restrict__ b_ih,
                  const float* __restrict__ b_hh,
                  float* __restrict__ xp,
                  int t0, int cT, int T)
{
    const int m = blockIdx.y;
    const int r = threadIdx.x;            // gate row 0..127
    const int tlo = blockIdx.x * XT;

    const float sc = (r < 64) ? -LOG2E : ((r < 96) ? TWO_LOG2E : -LOG2E);

    v2f w[7];
    const v2f* wp = (const v2f*)(W_ih + (size_t)(m * 128 + r) * D_IN);
    #pragma unroll
    for (int q = 0; q < 7; ++q) {
        v2f t = wp[q]; t.x *= sc; t.y *= sc; w[q] = t;
    }
    const float bs = (b_ih[m * 128 + r] + b_hh[m * 128 + r]) * sc;

    #pragma unroll
    for (int tt = 0; tt < XT; ++tt) {
        int t = tlo + tt;
        if (t >= cT) break;
        const v2f* xr = (const v2f*)(x + ((size_t)m * T + t0 + t) * D_IN);
        v2f acc = {bs, 0.0f};
        #pragma unroll
        for (int q = 0; q < 7; ++q) acc = __builtin_elementwise_fma(w[q], xr[q], acc);
        float* dst = xp + (((size_t)t * 4 + m) * 64 + (r & 63)) * 4 + (r >> 6) * 2;
        *(v2f*)dst = acc;   // unrounded v2f pair
    }
}

// ---------------- phase 2: sequential scan (4 blocks, 1 wave each) -------
// r10 structure; issue-trimmed: probed-select exchanges (exact), SALU-rolled
// prefetch pointer (no per-step VALU address math, no clamp — buffer padded
// by 8 steps), actB via per-lane-constant fma. Occupancy-1 declared so the
// allocator keeps the full live set resident.
__global__ __launch_bounds__(64) __attribute__((amdgpu_waves_per_eu(1, 1)))
void lstm_scan_m(const float* __restrict__ xp,
                 const float* __restrict__ W_hh,
                 float* __restrict__ carry,   // [0..127] h, [128..255] c
                 int cT, int first)
{
    const int m    = blockIdx.x;
    const int lane = threadIdx.x;      // 0..63
    const int hi   = lane >> 5;
    const int j    = lane & 31;
    const int rA   = lane;
    const int rB   = lane + 64;

    const float sA = -LOG2E;
    const float sB = hi ? -LOG2E : TWO_LOG2E;

    // Probe row_ror direction (slot s holds h[j16 | ((j15 + s*d0)&15)]).
    int d0;
    {
        int p = __builtin_amdgcn_mov_dpp(lane, 0x121, 0xf, 0xf, true);
        d0 = __builtin_amdgcn_readfirstlane(p);
    }
    const int j16 = j & 16, j15 = j & 15;
    int kk[16];
    #pragma unroll
    for (int s = 0; s < 16; ++s) kk[s] = j16 | ((j15 + s * d0) & 15);

    // Probe permlane16/32_swap direction -> per-lane "partner is in a" masks.
    unsigned long long mk16, mk32;
    {
        int a = lane, b;
        asm("v_mov_b32 %0, %1" : "=&v"(b) : "v"(lane));
        asm("v_permlane16_swap_b32 %0, %1" : "+v"(a), "+v"(b));
        mk16 = __ballot(a == (lane ^ 16));
        int a2 = lane, b2;
        asm("v_mov_b32 %0, %1" : "=&v"(b2) : "v"(lane));
        asm("v_permlane32_swap_b32 %0, %1" : "+v"(a2), "+v"(b2));
        mk32 = __ballot(a2 == (lane ^ 32));
    }

    // pre-permuted, prescaled W_hh fragments (own + partner rows)
    const float* WOA = W_hh + (size_t)(m * 128 + rA) * HID;
    const float* WOB = W_hh + (size_t)(m * 128 + rB) * HID;
    const float* WPA = W_hh + (size_t)(m * 128 + (rA ^ 16)) * HID;
    const float* WPB = W_hh + (size_t)(m * 128 + (rB ^ 16)) * HID;
    v2f wOA[8], wOB[8], wPA[8], wPB[8];
    #pragma unroll
    for (int q = 0; q < 8; ++q) {
        wOA[q] = (v2f){WOA[kk[2*q]] * sA, WOA[kk[2*q+1]] * sA};
        wOB[q] = (v2f){WOB[kk[2*q]] * sB, WOB[kk[2*q+1]] * sB};
        wPA[q] = (v2f){WPA[kk[2*q]] * sA, WPA[kk[2*q+1]] * sA};
        wPB[q] = (v2f){WPB[kk[2*q]] * sB, WPB[kk[2*q+1]] * sB};
    }

    // actB = fma(kB1, rBv, kB0): hi -> sigmoid(o)=r; lo -> tanh(g)=1-2r
    const float kB1 = hi ? 1.0f : -2.0f;
    const float kB0 = hi ? 0.0f : 1.0f;

    // xp stream: uniform rolling pointers (SGPR adds) + fixed per-lane offset
    const char* xbase = (const char*)xp + (size_t)m * 1024;   // chunk base, m-offset
    const char* pf    = xbase + (size_t)8 * 4096;             // prefetch ptr (t+8)
    const int   lofs  = lane * 16;                            // bytes

    float c, vh;
    if (first) { c = 0.0f; vh = 0.0f; }
    else       { vh = carry[m * 32 + j]; c = carry[128 + m * 32 + j]; }

    // ring-8 initial fill (cT is always a multiple of 8 and >= 8)
    v4f s0 = *(const v4f*)(xbase + 0 * 4096 + lofs);
    v4f s1 = *(const v4f*)(xbase + 1 * 4096 + lofs);
    v4f s2 = *(const v4f*)(xbase + 2 * 4096 + lofs);
    v4f s3 = *(const v4f*)(xbase + 3 * 4096 + lofs);
    v4f s4 = *(const v4f*)(xbase + 4 * 4096 + lofs);
    v4f s5 = *(const v4f*)(xbase + 5 * 4096 + lofs);
    v4f s6 = *(const v4f*)(xbase + 6 * 4096 + lofs);
    v4f s7 = *(const v4f*)(xbase + 7 * 4096 + lofs);

#define STEP(X)                                                                \
    {                                                                          \
        /* depth-1 gather: 15 independent row_ror DPPs of vh */                \
        float g1 = dppf<0x121>(vh), g2 = dppf<0x122>(vh);                      \
        float g3 = dppf<0x123>(vh), g4 = dppf<0x124>(vh);                      \
        float g5 = dppf<0x125>(vh), g6 = dppf<0x126>(vh);                      \
        float g7 = dppf<0x127>(vh), g8 = dppf<0x128>(vh);                      \
        float g9 = dppf<0x129>(vh), gA = dppf<0x12A>(vh);                      \
        float gB = dppf<0x12B>(vh), gC = dppf<0x12C>(vh);                      \
        float gD = dppf<0x12D>(vh), gE = dppf<0x12E>(vh);                      \
        float gF = dppf<0x12F>(vh);                                            \
        v2f hv[8];                                                             \
        hv[0] = (v2f){vh, g1}; hv[1] = (v2f){g2, g3};                          \
        hv[2] = (v2f){g4, g5}; hv[3] = (v2f){g6, g7};                          \
        hv[4] = (v2f){g8, g9}; hv[5] = (v2f){gA, gB};                          \
        hv[6] = (v2f){gC, gD}; hv[7] = (v2f){gE, gF};                          \
        /* 4 partial dots (K=16), seeded by the preloaded x-accumulators */    \
        v2f oa0 = (v2f){X.x, X.y}, oa1 = {0.0f, 0.0f};                         \
        v2f ob0 = (v2f){X.z, X.w}, ob1 = {0.0f, 0.0f};                         \
        v2f pa0 = {0.0f, 0.0f}, pa1 = {0.0f, 0.0f};                            \
        v2f pb0 = {0.0f, 0.0f}, pb1 = {0.0f, 0.0f};                            \
        _Pragma("unroll")                                                      \
        for (int q = 0; q < 8; q += 2) {                                       \
            oa0 = __builtin_elementwise_fma(wOA[q],     hv[q],     oa0);       \
            oa1 = __builtin_elementwise_fma(wOA[q + 1], hv[q + 1], oa1);       \
            ob0 = __builtin_elementwise_fma(wOB[q],     hv[q],     ob0);       \
            ob1 = __builtin_elementwise_fma(wOB[q + 1], hv[q + 1], ob1);       \
            pa0 = __builtin_elementwise_fma(wPA[q],     hv[q],     pa0);       \
            pa1 = __builtin_elementwise_fma(wPA[q + 1], hv[q + 1], pa1);       \
            pb0 = __builtin_elementwise_fma(wPB[q],     hv[q],     pb0);       \
            pb1 = __builtin_elementwise_fma(wPB[q + 1], hv[q + 1], pb1);       \
        }                                                                      \
        /* prefetch t+8 (uniform SGPR base walks 4096 B/step; pad covers end) */\
        X = *(const v4f*)(pf + lofs);                                          \
        pf += 4096;                                                            \
        v2f oas = oa0 + oa1, obs = ob0 + ob1;                                  \
        v2f pas = pa0 + pa1, pbs = pb0 + pb1;                                  \
        float qa = pas.x + pas.y, qb = pbs.x + pbs.y;                          \
        float ra = xchg16_sel(qa, mk16), rb = xchg16_sel(qb, mk16);            \
        float accA = (oas.x + oas.y) + ra;                                     \
        float accB = (obs.x + obs.y) + rb;                                     \
        float actA = rcpf(1.0f + exp2ff(accA));           /* sig(i)|sig(f) */  \
        float rBv  = rcpf(1.0f + exp2ff(accB));                                \
        float actB = __builtin_fmaf(kB1, rBv, kB0);       /* tanh(g)|sig(o) */ \
        float x0   = hi ? actA : actA * actB;             /* sig(f) | u */     \
        float y0   = xchg32_sel(x0,   mk32);              /* u | sig(f) */     \
        float y1   = xchg32_sel(actB, mk32);              /* so -> lo lanes */ \
        float sf   = hi ? actA : y0;                                           \
        float u    = hi ? y0   : x0;                                           \
        c = __builtin_fmaf(sf, c, u);                                          \
        float so = hi ? actB : y1;                                             \
        float r2 = rcpf(1.0f + exp2ff(c * TWO_LOG2E));                         \
        float tc = __builtin_fmaf(-2.0f, r2, 1.0f);                            \
        vh = so * tc;                       /* every lane: true h[j] */        \
    }

    const int iters = cT >> 3;
    for (int it = 0; it < iters; ++it) {
        STEP(s0) STEP(s1) STEP(s2) STEP(s3)
        STEP(s4) STEP(s5) STEP(s6) STEP(s7)
    }
#undef STEP

    // carry out h,c (hi lanes canonical; identical values in lo lanes)
    if (hi) {
        carry[m * 32 + j]       = vh;
        carry[128 + m * 32 + j] = c;
    }
}

// ---------------- phase 3: heads ----------------
__global__ __launch_bounds__(64)
void heads_kernel(const float* __restrict__ carry,
                  const float* __restrict__ Wt,  const float* __restrict__ bt,
                  const float* __restrict__ Wf1, const float* __restrict__ bf1,
                  const float* __restrict__ Wf2, const float* __restrict__ bf2,
                  float* __restrict__ out)
{
    const int tid = threadIdx.x;
    if (tid == 0) {
        float s = bt[0];
        #pragma unroll
        for (int k = 0; k < 128; ++k) s += carry[k] * Wt[k];
        out[0] = s;
    } else if (tid == 1) {
        float s = bf1[0];
        #pragma unroll
        for (int k = 0; k < 32; ++k) s += carry[32 + k] * Wf1[k];
        out[1] = s;
    } else if (tid == 2) {
        float s = bf2[0];
        #pragma unroll
        for (int k = 0; k < 32; ++k) s += carry[64 + k] * Wf2[k];
        out[2] = s;
    } else if (tid == 3) {
        float s = bf2[0];
        #pragma unroll
        for (int k = 0; k < 32; ++k) s += carry[96 + k] * Wf2[k];
        out[3] = s;
    }
}

extern "C" void kernel_launch(void* const* d_in, const int* in_sizes, int n_in,
                              void* d_out, int out_size, void* d_ws, size_t ws_size,
                              hipStream_t stream) {
    const float* x    = (const float*)d_in[0];
    const float* W_ih = (const float*)d_in[1];
    const float* W_hh = (const float*)d_in[2];
    const float* b_ih = (const float*)d_in[3];
    const float* b_hh = (const float*)d_in[4];
    const float* Wt   = (const float*)d_in[5];
    const float* bt   = (const float*)d_in[6];
    const float* Wf1  = (const float*)d_in[7];
    const float* bf1  = (const float*)d_in[8];
    const float* Wf2  = (const float*)d_in[9];
    const float* bf2  = (const float*)d_in[10];

    const int T = in_sizes[0] / (4 * D_IN);   // 16384

    float* carry = (float*)d_ws;                       // 256 floats
    float* xpbuf = (float*)((char*)d_ws + 1024);
    size_t avail = (ws_size > 1024) ? ws_size - 1024 : 0;

    // xp bytes per step: 4 LSTMs * 64 lanes * 16 B = 4096 B.
    // Reserve 8 pad steps for the tail prefetch over-read.
    long cmax = (long)(avail / 4096) - 8;
    cmax = (cmax / 8) * 8;
    if (cmax > T) cmax = T;
    if (cmax < 8) cmax = 8;                            // assume ws >= ~70 KB

    int nch = (T + (int)cmax - 1) / (int)cmax;
    int cT0 = (T + nch - 1) / nch;
    cT0 = ((cT0 + 7) / 8) * 8;
    if (cT0 > (int)cmax) cT0 = (int)cmax;

    int done = 0;
    while (done < T) {
        int cT = (T - done < cT0) ? (T - done) : cT0;
        dim3 gx((cT + XT - 1) / XT, 4);
        xproj_kernel<<<gx, 128, 0, stream>>>(x, W_ih, b_ih, b_hh, xpbuf,
                                             done, cT, T);
        lstm_scan_m<<<4, 64, 0, stream>>>(xpbuf, W_hh, carry,
                                          cT, done == 0 ? 1 : 0);
        done += cT;
    }
    heads_kernel<<<1, 64, 0, stream>>>(carry, Wt, bt, Wf1, bf1, Wf2, bf2,
                                       (float*)d_out);
}

// Round 14
// 3673.411 us; speedup vs baseline: 1.0423x; 1.0423x over previous
//
#include <hip/hip_runtime.h>

typedef float v2f __attribute__((ext_vector_type(2)));
typedef float v4f __attribute__((ext_vector_type(4)));

#define D_IN 14
#define HID  32
#define XT   16   // timesteps per xproj block

#define LOG2E      1.4426950408889634f
#define TWO_LOG2E  2.8853900817779268f

__device__ __forceinline__ float rcpf(float x) { return __builtin_amdgcn_rcpf(x); }

#if __has_builtin(__builtin_amdgcn_exp2f)
__device__ __forceinline__ float exp2ff(float x) { return __builtin_amdgcn_exp2f(x); }
#else
__device__ __forceinline__ float exp2ff(float x) { return exp2f(x); }
#endif

// DPP row_ror:N (0x120+N): independent depth-1 rotations within 16-lane rows.
template<int CTRL>
__device__ __forceinline__ float dppf(float x) {
    return __int_as_float(__builtin_amdgcn_mov_dpp(
        __float_as_int(x), CTRL, 0xf, 0xf, true));
}

// Direction-proof exchanges (proven r3/r5/r7/r9/r10: with a=b=x the pair
// {a,b} holds the two half-swapped copies in either order, so (a+b)-x ==
// partner's value under either direction convention, +<=1ulp).
__device__ __forceinline__ float xchg32(float x) {
    float a = x, b;
    asm("v_mov_b32 %0, %1" : "=&v"(b) : "v"(x));
    asm("v_permlane32_swap_b32 %0, %1" : "+v"(a), "+v"(b));
    return (a + b) - x;
}
__device__ __forceinline__ float xchg16(float x) {
    float a = x, b;
    asm("v_mov_b32 %0, %1" : "=&v"(b) : "v"(x));
    asm("v_permlane16_swap_b32 %0, %1" : "+v"(a), "+v"(b));
    return (a + b) - x;
}

// ---------------- phase 1: x projection (parallel, bit-exact) ----------
// Computes EXACTLY the v2f accumulator r9's in-loop x-part produced:
//   acc = {bias*sc, 0}; 7x acc = fma(w*sc, x2, acc)   (v2f lanes kept!)
// and stores the UNROUNDED pair. Layout: xp[t][m][lane 0..63][4] floats,
// where lane slot = {accA.x, accA.y, accB.x, accB.y} for rows (lane, lane+64).
__global__ __launch_bounds__(128)
void xproj_kernel(const float* __restrict__ x,
                  const float* __restrict__ W_ih,
                  const float* __restrict__ b_ih,
                  const float* __restrict__ b_hh,
                  float* __restrict__ xp,
                  int t0, int cT, int T)
{
    const int m = blockIdx.y;
    const int r = threadIdx.x;            // gate row 0..127
    const int tlo = blockIdx.x * XT;

    const float sc = (r < 64) ? -LOG2E : ((r < 96) ? TWO_LOG2E : -LOG2E);

    v2f w[7];
    const v2f* wp = (const v2f*)(W_ih + (size_t)(m * 128 + r) * D_IN);
    #pragma unroll
    for (int q = 0; q < 7; ++q) {
        v2f t = wp[q]; t.x *= sc; t.y *= sc; w[q] = t;
    }
    const float bs = (b_ih[m * 128 + r] + b_hh[m * 128 + r]) * sc;

    #pragma unroll
    for (int tt = 0; tt < XT; ++tt) {
        int t = tlo + tt;
        if (t >= cT) break;
        const v2f* xr = (const v2f*)(x + ((size_t)m * T + t0 + t) * D_IN);
        v2f acc = {bs, 0.0f};
        #pragma unroll
        for (int q = 0; q < 7; ++q) acc = __builtin_elementwise_fma(w[q], xr[q], acc);
        float* dst = xp + (((size_t)t * 4 + m) * 64 + (r & 63)) * 4 + (r >> 6) * 2;
        *(v2f*)dst = acc;   // unrounded v2f pair
    }
}

// ---------------- phase 2: sequential scan (4 blocks, 1 wave each) -------
// Math bit-identical to round 9 (passed, absmax 0.0): same DPP gather, same
// partner-row split, same exchanges and activations. Only change: the x-part
// v2f accumulators arrive preloaded from xp (one dwordx4 per lane per step,
// ring-8 prefetched). Persistent register demand ~130 (was ~150+ with W_ih).
__global__ __launch_bounds__(64, 1)
void lstm_scan_m(const float* __restrict__ xp,
                 const float* __restrict__ W_hh,
                 float* __restrict__ carry,   // [0..127] h, [128..255] c
                 int cT, int first)
{
    const int m    = blockIdx.x;
    const int lane = threadIdx.x;      // 0..63
    const int hi   = lane >> 5;
    const int j    = lane & 31;
    const int rA   = lane;
    const int rB   = lane + 64;

    const float sA = -LOG2E;
    const float sB = hi ? -LOG2E : TWO_LOG2E;

    // Probe row_ror direction (slot s holds h[j16 | ((j15 + s*d0)&15)]).
    int d0;
    {
        int p = __builtin_amdgcn_mov_dpp(lane, 0x121, 0xf, 0xf, true);
        d0 = __builtin_amdgcn_readfirstlane(p);
    }
    const int j16 = j & 16, j15 = j & 15;
    int kk[16];
    #pragma unroll
    for (int s = 0; s < 16; ++s) kk[s] = j16 | ((j15 + s * d0) & 15);

    // pre-permuted, prescaled W_hh fragments (own + partner rows)
    const float* WOA = W_hh + (size_t)(m * 128 + rA) * HID;
    const float* WOB = W_hh + (size_t)(m * 128 + rB) * HID;
    const float* WPA = W_hh + (size_t)(m * 128 + (rA ^ 16)) * HID;
    const float* WPB = W_hh + (size_t)(m * 128 + (rB ^ 16)) * HID;
    v2f wOA[8], wOB[8], wPA[8], wPB[8];
    #pragma unroll
    for (int q = 0; q < 8; ++q) {
        wOA[q] = (v2f){WOA[kk[2*q]] * sA, WOA[kk[2*q+1]] * sA};
        wOB[q] = (v2f){WOB[kk[2*q]] * sB, WOB[kk[2*q+1]] * sB};
        wPA[q] = (v2f){WPA[kk[2*q]] * sA, WPA[kk[2*q+1]] * sA};
        wPB[q] = (v2f){WPB[kk[2*q]] * sB, WPB[kk[2*q+1]] * sB};
    }

    // per-lane xp stream: v4f index (t*256 + m*64 + lane)
    const v4f* xpv = (const v4f*)xp + (size_t)m * 64 + lane;

    float c, vh;
    if (first) { c = 0.0f; vh = 0.0f; }
    else       { vh = carry[m * 32 + j]; c = carry[128 + m * 32 + j]; }

    // ring-8 prefetch (static slot names -> stays in registers)
    v4f s0, s1, s2, s3, s4, s5, s6, s7;
    {
        int e = cT - 1;
        s0 = xpv[(size_t)((0 < e) ? 0 : e) * 256];
        s1 = xpv[(size_t)((1 < e) ? 1 : e) * 256];
        s2 = xpv[(size_t)((2 < e) ? 2 : e) * 256];
        s3 = xpv[(size_t)((3 < e) ? 3 : e) * 256];
        s4 = xpv[(size_t)((4 < e) ? 4 : e) * 256];
        s5 = xpv[(size_t)((5 < e) ? 5 : e) * 256];
        s6 = xpv[(size_t)((6 < e) ? 6 : e) * 256];
        s7 = xpv[(size_t)((7 < e) ? 7 : e) * 256];
    }

#define STEP(t, X)                                                             \
    {                                                                          \
        /* depth-1 gather: 15 independent row_ror DPPs of vh */                \
        float g1 = dppf<0x121>(vh), g2 = dppf<0x122>(vh);                      \
        float g3 = dppf<0x123>(vh), g4 = dppf<0x124>(vh);                      \
        float g5 = dppf<0x125>(vh), g6 = dppf<0x126>(vh);                      \
        float g7 = dppf<0x127>(vh), g8 = dppf<0x128>(vh);                      \
        float g9 = dppf<0x129>(vh), gA = dppf<0x12A>(vh);                      \
        float gB = dppf<0x12B>(vh), gC = dppf<0x12C>(vh);                      \
        float gD = dppf<0x12D>(vh), gE = dppf<0x12E>(vh);                      \
        float gF = dppf<0x12F>(vh);                                            \
        v2f hv[8];                                                             \
        hv[0] = (v2f){vh, g1}; hv[1] = (v2f){g2, g3};                          \
        hv[2] = (v2f){g4, g5}; hv[3] = (v2f){g6, g7};                          \
        hv[4] = (v2f){g8, g9}; hv[5] = (v2f){gA, gB};                          \
        hv[6] = (v2f){gC, gD}; hv[7] = (v2f){gE, gF};                          \
        /* 4 partial dots (K=16), seeded by the PRELOADED x-accumulators */    \
        v2f oa0 = (v2f){X.x, X.y}, oa1 = {0.0f, 0.0f};                         \
        v2f ob0 = (v2f){X.z, X.w}, ob1 = {0.0f, 0.0f};                         \
        v2f pa0 = {0.0f, 0.0f}, pa1 = {0.0f, 0.0f};                            \
        v2f pb0 = {0.0f, 0.0f}, pb1 = {0.0f, 0.0f};                            \
        _Pragma("unroll")                                                      \
        for (int q = 0; q < 8; q += 2) {                                       \
            oa0 = __builtin_elementwise_fma(wOA[q],     hv[q],     oa0);       \
            oa1 = __builtin_elementwise_fma(wOA[q + 1], hv[q + 1], oa1);       \
            ob0 = __builtin_elementwise_fma(wOB[q],     hv[q],     ob0);       \
            ob1 = __builtin_elementwise_fma(wOB[q + 1], hv[q + 1], ob1);       \
            pa0 = __builtin_elementwise_fma(wPA[q],     hv[q],     pa0);       \
            pa1 = __builtin_elementwise_fma(wPA[q + 1], hv[q + 1], pa1);       \
            pb0 = __builtin_elementwise_fma(wPB[q],     hv[q],     pb0);       \
            pb1 = __builtin_elementwise_fma(wPB[q + 1], hv[q + 1], pb1);       \
        }                                                                      \
        /* prefetch xp for t+8 into the slot just consumed */                  \
        {                                                                      \
            int tn = (t) + 8; tn = (tn < cT) ? tn : (cT - 1);                  \
            X = xpv[(size_t)tn * 256];                                         \
        }                                                                      \
        v2f oas = oa0 + oa1, obs = ob0 + ob1;                                  \
        v2f pas = pa0 + pa1, pbs = pb0 + pb1;                                  \
        float qa = pas.x + pas.y, qb = pbs.x + pbs.y;                          \
        float ra = xchg16(qa), rb = xchg16(qb);   /* complete K=32 */          \
        float accA = (oas.x + oas.y) + ra;                                     \
        float accB = (obs.x + obs.y) + rb;                                     \
        float actA = rcpf(1.0f + exp2ff(accA));           /* sig(i)|sig(f) */  \
        float rBv  = rcpf(1.0f + exp2ff(accB));                                \
        float actB = hi ? rBv : __builtin_fmaf(-2.0f, rBv, 1.0f);              \
        float x0   = hi ? actA : actA * actB;             /* sig(f) | u */     \
        float y0   = xchg32(x0);                          /* u | sig(f) */     \
        float y1   = xchg32(actB);                        /* so -> lo lanes */ \
        float sf   = hi ? actA : y0;                                           \
        float u    = hi ? y0   : x0;                                           \
        c = __builtin_fmaf(sf, c, u);                                          \
        float so = hi ? actB : y1;                                             \
        float r2 = rcpf(1.0f + exp2ff(c * TWO_LOG2E));                         \
        float tc = __builtin_fmaf(-2.0f, r2, 1.0f);                            \
        vh = so * tc;                       /* every lane: true h[j] */        \
    }

    int t = 0;
    for (; t + 8 <= cT; t += 8) {
        STEP(t,     s0)
        STEP(t + 1, s1)
        STEP(t + 2, s2)
        STEP(t + 3, s3)
        STEP(t + 4, s4)
        STEP(t + 5, s5)
        STEP(t + 6, s6)
        STEP(t + 7, s7)
    }
    for (; t < cT; ++t) {   // defensive tail (cT kept a multiple of 8)
        v4f q4 = xpv[(size_t)t * 256];
        STEP(t, q4)
    }
#undef STEP

    // carry out h,c (hi lanes canonical; identical values in lo lanes)
    if (hi) {
        carry[m * 32 + j]       = vh;
        carry[128 + m * 32 + j] = c;
    }
}

// ---------------- phase 3: heads ----------------
__global__ __launch_bounds__(64)
void heads_kernel(const float* __restrict__ carry,
                  const float* __restrict__ Wt,  const float* __restrict__ bt,
                  const float* __restrict__ Wf1, const float* __restrict__ bf1,
                  const float* __restrict__ Wf2, const float* __restrict__ bf2,
                  float* __restrict__ out)
{
    const int tid = threadIdx.x;
    if (tid == 0) {
        float s = bt[0];
        #pragma unroll
        for (int k = 0; k < 128; ++k) s += carry[k] * Wt[k];
        out[0] = s;
    } else if (tid == 1) {
        float s = bf1[0];
        #pragma unroll
        for (int k = 0; k < 32; ++k) s += carry[32 + k] * Wf1[k];
        out[1] = s;
    } else if (tid == 2) {
        float s = bf2[0];
        #pragma unroll
        for (int k = 0; k < 32; ++k) s += carry[64 + k] * Wf2[k];
        out[2] = s;
    } else if (tid == 3) {
        float s = bf2[0];
        #pragma unroll
        for (int k = 0; k < 32; ++k) s += carry[96 + k] * Wf2[k];
        out[3] = s;
    }
}

extern "C" void kernel_launch(void* const* d_in, const int* in_sizes, int n_in,
                              void* d_out, int out_size, void* d_ws, size_t ws_size,
                              hipStream_t stream) {
    const float* x    = (const float*)d_in[0];
    const float* W_ih = (const float*)d_in[1];
    const float* W_hh = (const float*)d_in[2];
    const float* b_ih = (const float*)d_in[3];
    const float* b_hh = (const float*)d_in[4];
    const float* Wt   = (const float*)d_in[5];
    const float* bt   = (const float*)d_in[6];
    const float* Wf1  = (const float*)d_in[7];
    const float* bf1  = (const float*)d_in[8];
    const float* Wf2  = (const float*)d_in[9];
    const float* bf2  = (const float*)d_in[10];

    const int T = in_sizes[0] / (4 * D_IN);   // 16384

    float* carry = (float*)d_ws;                       // 256 floats
    float* xpbuf = (float*)((char*)d_ws + 1024);
    size_t avail = (ws_size > 1024) ? ws_size - 1024 : 0;

    // xp bytes per step: 4 LSTMs * 64 lanes * 16 B = 4096 B
    long cmax = (long)(avail / 4096);
    cmax = (cmax / 8) * 8;
    if (cmax > T) cmax = T;
    if (cmax < 8) cmax = 8;                            // assume ws >= ~40 KB

    int nch = (T + (int)cmax - 1) / (int)cmax;
    int cT0 = (T + nch - 1) / nch;
    cT0 = ((cT0 + 7) / 8) * 8;
    if (cT0 > (int)cmax) cT0 = (int)cmax;

    int done = 0;
    while (done < T) {
        int cT = (T - done < cT0) ? (T - done) : cT0;
        dim3 gx((cT + XT - 1) / XT, 4);
        xproj_kernel<<<gx, 128, 0, stream>>>(x, W_ih, b_ih, b_hh, xpbuf,
                                             done, cT, T);
        lstm_scan_m<<<4, 64, 0, stream>>>(xpbuf, W_hh, carry,
                                          cT, done == 0 ? 1 : 0);
        done += cT;
    }
    heads_kernel<<<1, 64, 0, stream>>>(carry, Wt, bt, Wf1, bf1, Wf2, bf2,
                                       (float*)d_out);
}

// Round 15
// 3671.779 us; speedup vs baseline: 1.0427x; 1.0004x over previous
//
#include <hip/hip_runtime.h>

typedef float v2f __attribute__((ext_vector_type(2)));
typedef float v4f __attribute__((ext_vector_type(4)));

#define D_IN 14
#define HID  32
#define XT   16   // timesteps per xproj block

#define LOG2E      1.4426950408889634f
#define TWO_LOG2E  2.8853900817779268f

__device__ __forceinline__ float rcpf(float x) { return __builtin_amdgcn_rcpf(x); }

#if __has_builtin(__builtin_amdgcn_exp2f)
__device__ __forceinline__ float exp2ff(float x) { return __builtin_amdgcn_exp2f(x); }
#else
__device__ __forceinline__ float exp2ff(float x) { return exp2f(x); }
#endif

// DPP row_ror:N (0x120+N): independent depth-1 rotations within 16-lane rows.
template<int CTRL>
__device__ __forceinline__ float dppf(float x) {
    return __int_as_float(__builtin_amdgcn_mov_dpp(
        __float_as_int(x), CTRL, 0xf, 0xf, true));
}

// Direction-proof exchanges (proven r3/r5/r7/r9/r10/r14: with a=b=x the pair
// {a,b} holds the two half-swapped copies in either order, so (a+b)-x ==
// partner's value under either direction convention, +<=1ulp). These are
// value-deterministic under ANY register allocation (add is commutative),
// unlike the probed-select variant (r13 failure).
__device__ __forceinline__ float xchg32(float x) {
    float a = x, b;
    asm("v_mov_b32 %0, %1" : "=&v"(b) : "v"(x));
    asm("v_permlane32_swap_b32 %0, %1" : "+v"(a), "+v"(b));
    return (a + b) - x;
}
__device__ __forceinline__ float xchg16(float x) {
    float a = x, b;
    asm("v_mov_b32 %0, %1" : "=&v"(b) : "v"(x));
    asm("v_permlane16_swap_b32 %0, %1" : "+v"(a), "+v"(b));
    return (a + b) - x;
}

// ---------------- phase 1: x projection (parallel, bit-exact) ----------
// Computes EXACTLY the v2f accumulator r9's in-loop x-part produced:
//   acc = {bias*sc, 0}; 7x acc = fma(w*sc, x2, acc)   (v2f lanes kept!)
// and stores the UNROUNDED pair. Layout: xp[t][m][lane 0..63][4] floats,
// where lane slot = {accA.x, accA.y, accB.x, accB.y} for rows (lane, lane+64).
__global__ __launch_bounds__(128)
void xproj_kernel(const float* __restrict__ x,
                  const float* __restrict__ W_ih,
                  const float* __restrict__ b_ih,
                  const float* __restrict__ b_hh,
                  float* __restrict__ xp,
                  int t0, int cT, int T)
{
    const int m = blockIdx.y;
    const int r = threadIdx.x;            // gate row 0..127
    const int tlo = blockIdx.x * XT;

    const float sc = (r < 64) ? -LOG2E : ((r < 96) ? TWO_LOG2E : -LOG2E);

    v2f w[7];
    const v2f* wp = (const v2f*)(W_ih + (size_t)(m * 128 + r) * D_IN);
    #pragma unroll
    for (int q = 0; q < 7; ++q) {
        v2f t = wp[q]; t.x *= sc; t.y *= sc; w[q] = t;
    }
    const float bs = (b_ih[m * 128 + r] + b_hh[m * 128 + r]) * sc;

    #pragma unroll
    for (int tt = 0; tt < XT; ++tt) {
        int t = tlo + tt;
        if (t >= cT) break;
        const v2f* xr = (const v2f*)(x + ((size_t)m * T + t0 + t) * D_IN);
        v2f acc = {bs, 0.0f};
        #pragma unroll
        for (int q = 0; q < 7; ++q) acc = __builtin_elementwise_fma(w[q], xr[q], acc);
        float* dst = xp + (((size_t)t * 4 + m) * 64 + (r & 63)) * 4 + (r >> 6) * 2;
        *(v2f*)dst = acc;   // unrounded v2f pair
    }
}

// ---------------- phase 2: sequential scan (4 blocks, 1 wave each) -------
// Math identical to rounds 10/14 (passed, absmax 9.77e-4, deterministic).
// ONLY change vs r14: amdgpu_waves_per_eu(1,1) — tells the allocator the
// occupancy target is exactly 1 wave/EU, so the full persistent live set
// (weights 64 VGPR + ring-8 32 VGPR + transients) stays register-resident
// instead of being partially re-loaded from L2 each step (VGPR 72 -> ~132).
// All FP ops here are fixed-order builtins/asm whose VALUES are independent
// of register allocation, so this decoration cannot change the trajectory.
__global__ __launch_bounds__(64, 1) __attribute__((amdgpu_waves_per_eu(1, 1)))
void lstm_scan_m(const float* __restrict__ xp,
                 const float* __restrict__ W_hh,
                 float* __restrict__ carry,   // [0..127] h, [128..255] c
                 int cT, int first)
{
    const int m    = blockIdx.x;
    const int lane = threadIdx.x;      // 0..63
    const int hi   = lane >> 5;
    const int j    = lane & 31;
    const int rA   = lane;
    const int rB   = lane + 64;

    const float sA = -LOG2E;
    const float sB = hi ? -LOG2E : TWO_LOG2E;

    // Probe row_ror direction (slot s holds h[j16 | ((j15 + s*d0)&15)]).
    int d0;
    {
        int p = __builtin_amdgcn_mov_dpp(lane, 0x121, 0xf, 0xf, true);
        d0 = __builtin_amdgcn_readfirstlane(p);
    }
    const int j16 = j & 16, j15 = j & 15;
    int kk[16];
    #pragma unroll
    for (int s = 0; s < 16; ++s) kk[s] = j16 | ((j15 + s * d0) & 15);

    // pre-permuted, prescaled W_hh fragments (own + partner rows)
    const float* WOA = W_hh + (size_t)(m * 128 + rA) * HID;
    const float* WOB = W_hh + (size_t)(m * 128 + rB) * HID;
    const float* WPA = W_hh + (size_t)(m * 128 + (rA ^ 16)) * HID;
    const float* WPB = W_hh + (size_t)(m * 128 + (rB ^ 16)) * HID;
    v2f wOA[8], wOB[8], wPA[8], wPB[8];
    #pragma unroll
    for (int q = 0; q < 8; ++q) {
        wOA[q] = (v2f){WOA[kk[2*q]] * sA, WOA[kk[2*q+1]] * sA};
        wOB[q] = (v2f){WOB[kk[2*q]] * sB, WOB[kk[2*q+1]] * sB};
        wPA[q] = (v2f){WPA[kk[2*q]] * sA, WPA[kk[2*q+1]] * sA};
        wPB[q] = (v2f){WPB[kk[2*q]] * sB, WPB[kk[2*q+1]] * sB};
    }

    // per-lane xp stream: v4f index (t*256 + m*64 + lane)
    const v4f* xpv = (const v4f*)xp + (size_t)m * 64 + lane;

    float c, vh;
    if (first) { c = 0.0f; vh = 0.0f; }
    else       { vh = carry[m * 32 + j]; c = carry[128 + m * 32 + j]; }

    // ring-8 prefetch (static slot names -> stays in registers)
    v4f s0, s1, s2, s3, s4, s5, s6, s7;
    {
        int e = cT - 1;
        s0 = xpv[(size_t)((0 < e) ? 0 : e) * 256];
        s1 = xpv[(size_t)((1 < e) ? 1 : e) * 256];
        s2 = xpv[(size_t)((2 < e) ? 2 : e) * 256];
        s3 = xpv[(size_t)((3 < e) ? 3 : e) * 256];
        s4 = xpv[(size_t)((4 < e) ? 4 : e) * 256];
        s5 = xpv[(size_t)((5 < e) ? 5 : e) * 256];
        s6 = xpv[(size_t)((6 < e) ? 6 : e) * 256];
        s7 = xpv[(size_t)((7 < e) ? 7 : e) * 256];
    }

#define STEP(t, X)                                                             \
    {                                                                          \
        /* depth-1 gather: 15 independent row_ror DPPs of vh */                \
        float g1 = dppf<0x121>(vh), g2 = dppf<0x122>(vh);                      \
        float g3 = dppf<0x123>(vh), g4 = dppf<0x124>(vh);                      \
        float g5 = dppf<0x125>(vh), g6 = dppf<0x126>(vh);                      \
        float g7 = dppf<0x127>(vh), g8 = dppf<0x128>(vh);                      \
        float g9 = dppf<0x129>(vh), gA = dppf<0x12A>(vh);                      \
        float gB = dppf<0x12B>(vh), gC = dppf<0x12C>(vh);                      \
        float gD = dppf<0x12D>(vh), gE = dppf<0x12E>(vh);                      \
        float gF = dppf<0x12F>(vh);                                            \
        v2f hv[8];                                                             \
        hv[0] = (v2f){vh, g1}; hv[1] = (v2f){g2, g3};                          \
        hv[2] = (v2f){g4, g5}; hv[3] = (v2f){g6, g7};                          \
        hv[4] = (v2f){g8, g9}; hv[5] = (v2f){gA, gB};                          \
        hv[6] = (v2f){gC, gD}; hv[7] = (v2f){gE, gF};                          \
        /* 4 partial dots (K=16), seeded by the PRELOADED x-accumulators */    \
        v2f oa0 = (v2f){X.x, X.y}, oa1 = {0.0f, 0.0f};                         \
        v2f ob0 = (v2f){X.z, X.w}, ob1 = {0.0f, 0.0f};                         \
        v2f pa0 = {0.0f, 0.0f}, pa1 = {0.0f, 0.0f};                            \
        v2f pb0 = {0.0f, 0.0f}, pb1 = {0.0f, 0.0f};                            \
        _Pragma("unroll")                                                      \
        for (int q = 0; q < 8; q += 2) {                                       \
            oa0 = __builtin_elementwise_fma(wOA[q],     hv[q],     oa0);       \
            oa1 = __builtin_elementwise_fma(wOA[q + 1], hv[q + 1], oa1);       \
            ob0 = __builtin_elementwise_fma(wOB[q],     hv[q],     ob0);       \
            ob1 = __builtin_elementwise_fma(wOB[q + 1], hv[q + 1], ob1);       \
            pa0 = __builtin_elementwise_fma(wPA[q],     hv[q],     pa0);       \
            pa1 = __builtin_elementwise_fma(wPA[q + 1], hv[q + 1], pa1);       \
            pb0 = __builtin_elementwise_fma(wPB[q],     hv[q],     pb0);       \
            pb1 = __builtin_elementwise_fma(wPB[q + 1], hv[q + 1], pb1);       \
        }                                                                      \
        /* prefetch xp for t+8 into the slot just consumed */                  \
        {                                                                      \
            int tn = (t) + 8; tn = (tn < cT) ? tn : (cT - 1);                  \
            X = xpv[(size_t)tn * 256];                                         \
        }                                                                      \
        v2f oas = oa0 + oa1, obs = ob0 + ob1;                                  \
        v2f pas = pa0 + pa1, pbs = pb0 + pb1;                                  \
        float qa = pas.x + pas.y, qb = pbs.x + pbs.y;                          \
        float ra = xchg16(qa), rb = xchg16(qb);   /* complete K=32 */          \
        float accA = (oas.x + oas.y) + ra;                                     \
        float accB = (obs.x + obs.y) + rb;                                     \
        float actA = rcpf(1.0f + exp2ff(accA));           /* sig(i)|sig(f) */  \
        float rBv  = rcpf(1.0f + exp2ff(accB));                                \
        float actB = hi ? rBv : __builtin_fmaf(-2.0f, rBv, 1.0f);              \
        float x0   = hi ? actA : actA * actB;             /* sig(f) | u */     \
        float y0   = xchg32(x0);                          /* u | sig(f) */     \
        float y1   = xchg32(actB);                        /* so -> lo lanes */ \
        float sf   = hi ? actA : y0;                                           \
        float u    = hi ? y0   : x0;                                           \
        c = __builtin_fmaf(sf, c, u);                                          \
        float so = hi ? actB : y1;                                             \
        float r2 = rcpf(1.0f + exp2ff(c * TWO_LOG2E));                         \
        float tc = __builtin_fmaf(-2.0f, r2, 1.0f);                            \
        vh = so * tc;                       /* every lane: true h[j] */        \
    }

    int t = 0;
    for (; t + 8 <= cT; t += 8) {
        STEP(t,     s0)
        STEP(t + 1, s1)
        STEP(t + 2, s2)
        STEP(t + 3, s3)
        STEP(t + 4, s4)
        STEP(t + 5, s5)
        STEP(t + 6, s6)
        STEP(t + 7, s7)
    }
    for (; t < cT; ++t) {   // defensive tail (cT kept a multiple of 8)
        v4f q4 = xpv[(size_t)t * 256];
        STEP(t, q4)
    }
#undef STEP

    // carry out h,c (hi lanes canonical; identical values in lo lanes)
    if (hi) {
        carry[m * 32 + j]       = vh;
        carry[128 + m * 32 + j] = c;
    }
}

// ---------------- phase 3: heads ----------------
__global__ __launch_bounds__(64)
void heads_kernel(const float* __restrict__ carry,
                  const float* __restrict__ Wt,  const float* __restrict__ bt,
                  const float* __restrict__ Wf1, const float* __restrict__ bf1,
                  const float* __restrict__ Wf2, const float* __restrict__ bf2,
                  float* __restrict__ out)
{
    const int tid = threadIdx.x;
    if (tid == 0) {
        float s = bt[0];
        #pragma unroll
        for (int k = 0; k < 128; ++k) s += carry[k] * Wt[k];
        out[0] = s;
    } else if (tid == 1) {
        float s = bf1[0];
        #pragma unroll
        for (int k = 0; k < 32; ++k) s += carry[32 + k] * Wf1[k];
        out[1] = s;
    } else if (tid == 2) {
        float s = bf2[0];
        #pragma unroll
        for (int k = 0; k < 32; ++k) s += carry[64 + k] * Wf2[k];
        out[2] = s;
    } else if (tid == 3) {
        float s = bf2[0];
        #pragma unroll
        for (int k = 0; k < 32; ++k) s += carry[96 + k] * Wf2[k];
        out[3] = s;
    }
}

extern "C" void kernel_launch(void* const* d_in, const int* in_sizes, int n_in,
                              void* d_out, int out_size, void* d_ws, size_t ws_size,
                              hipStream_t stream) {
    const float* x    = (const float*)d_in[0];
    const float* W_ih = (const float*)d_in[1];
    const float* W_hh = (const float*)d_in[2];
    const float* b_ih = (const float*)d_in[3];
    const float* b_hh = (const float*)d_in[4];
    const float* Wt   = (const float*)d_in[5];
    const float* bt   = (const float*)d_in[6];
    const float* Wf1  = (const float*)d_in[7];
    const float* bf1  = (const float*)d_in[8];
    const float* Wf2  = (const float*)d_in[9];
    const float* bf2  = (const float*)d_in[10];

    const int T = in_sizes[0] / (4 * D_IN);   // 16384

    float* carry = (float*)d_ws;                       // 256 floats
    float* xpbuf = (float*)((char*)d_ws + 1024);
    size_t avail = (ws_size > 1024) ? ws_size - 1024 : 0;

    // xp bytes per step: 4 LSTMs * 64 lanes * 16 B = 4096 B
    long cmax = (long)(avail / 4096);
    cmax = (cmax / 8) * 8;
    if (cmax > T) cmax = T;
    if (cmax < 8) cmax = 8;                            // assume ws >= ~40 KB

    int nch = (T + (int)cmax - 1) / (int)cmax;
    int cT0 = (T + nch - 1) / nch;
    cT0 = ((cT0 + 7) / 8) * 8;
    if (cT0 > (int)cmax) cT0 = (int)cmax;

    int done = 0;
    while (done < T) {
        int cT = (T - done < cT0) ? (T - done) : cT0;
        dim3 gx((cT + XT - 1) / XT, 4);
        xproj_kernel<<<gx, 128, 0, stream>>>(x, W_ih, b_ih, b_hh, xpbuf,
                                             done, cT, T);
        lstm_scan_m<<<4, 64, 0, stream>>>(xpbuf, W_hh, carry,
                                          cT, done == 0 ? 1 : 0);
        done += cT;
    }
    heads_kernel<<<1, 64, 0, stream>>>(carry, Wt, bt, Wf1, bf1, Wf2, bf2,
                                       (float*)d_out);
}